// Round 11
// baseline (48.969 us; speedup 1.0000x reference)
//
#include <hip/hip_runtime.h>

#define BB 4
#define CIN 3
#define HH 512
#define WW 512
#define KK 9
#define COUT 3
#define HO 510
#define WO 510
#define HW (HH * WW)
#define HOWO (HO * WO)

// padded f16 NHWC PAIR buffer: element (y,x) = {c0,c1,c2,0 | c0',c1',c2',0}
// (primes = pixel x+1). rows -3..514 (PADR=3), cols -4..515 (PADC=4).
#define PR 518
#define PC 520
#define PADR 3
#define PADC 4
#define XP_BYTES ((size_t)BB * PR * PC * sizeof(uint4))

typedef __fp16 h2 __attribute__((ext_vector_type(2)));

__device__ __forceinline__ h2 pkrtz(float a, float b) {
    return __builtin_amdgcn_cvt_pkrtz(a, b);
}
__device__ __forceinline__ float fdot2f(h2 a, h2 b, float c) {
    return __builtin_amdgcn_fdot2(a, b, c, false);
}
__device__ __forceinline__ h2 uint_as_h2(unsigned u) {
    return __builtin_bit_cast(h2, u);
}
__device__ __forceinline__ unsigned h2_as_uint(h2 h) {
    return __builtin_bit_cast(unsigned, h);
}
// w1 element: channel ch, input channel c, kernel row r, col s
__device__ __forceinline__ float w1e(const float* w1, int ch, int c, int r, int s) {
    return w1[ch * 27 + c * 9 + r * 3 + s];
}

// ---------------- kernel 1: NCHW f32 -> padded f16 NHWC pair ----------------
__global__ __launch_bounds__(256) void repack_pairh(
    const float* __restrict__ x, uint4* __restrict__ xp)
{
    const int idx = blockIdx.x * blockDim.x + threadIdx.x;
    const int total = BB * PR * PC;
    if (idx >= total) return;
    const int b = idx / (PR * PC);
    const int rem = idx - b * (PR * PC);
    const int y = rem / PC;
    const int xc = rem - y * PC;
    const int ys = y - PADR;
    const float* xb = x + (size_t)b * CIN * HW;
    float c[2][3] = {{0.f, 0.f, 0.f}, {0.f, 0.f, 0.f}};
#pragma unroll
    for (int q = 0; q < 2; ++q) {
        const int xs = xc - PADC + q;
        if ((unsigned)ys < (unsigned)HH && (unsigned)xs < (unsigned)WW) {
            const int p = ys * WW + xs;
            c[q][0] = xb[p];
            c[q][1] = xb[HW + p];
            c[q][2] = xb[2 * HW + p];
        }
    }
    uint4 v;
    v.x = h2_as_uint(pkrtz(c[0][0], c[0][1]));
    v.y = h2_as_uint(pkrtz(c[0][2], 0.f));
    v.z = h2_as_uint(pkrtz(c[1][0], c[1][1]));
    v.w = h2_as_uint(pkrtz(c[1][2], 0.f));
    xp[idx] = v;
}

// -- kernel 2: fused; A: conv1 -> 18 packed dwords; B: pair-gather + pk math --
__global__ __launch_bounds__(256) void deform_fused6(
    const uint4* __restrict__ xp,   // [B][PR][PC] padded f16 pair
    const float* __restrict__ w1,   // [18][3][3][3]
    const float* __restrict__ b1,   // [18]
    const float* __restrict__ w2,   // [3][3][3][3]
    const float* __restrict__ b2,   // [3]
    float* __restrict__ out)        // [B][3][HO][WO]
{
    // conv1 weights: s_w1h[k*9+pos] = {wy_c01, wy_c2x, wx_c01, wx_c2x}
    __shared__ uint4 s_w1h[KK * 9];
    __shared__ float s_b[18];
    // conv2 weights packed h2: per tap k, wa = {o0_c01,o0_c2x,o1_c01,o1_c2x},
    // wb = {o2_c01, o2_c2x}
    __shared__ uint4 s_w2a[KK];
    __shared__ uint2 s_w2b[KK];
    __shared__ float s_b2[COUT];

    if (threadIdx.x < KK * 9) {
        const int k = threadIdx.x / 9;
        const int pos = threadIdx.x % 9;
        const int r = pos / 3, s = pos % 3;
        uint4 u;
        u.x = h2_as_uint(pkrtz(w1e(w1, 2 * k, 0, r, s), w1e(w1, 2 * k, 1, r, s)));
        u.y = h2_as_uint(pkrtz(w1e(w1, 2 * k, 2, r, s), 0.f));
        u.z = h2_as_uint(pkrtz(w1e(w1, 2 * k + 1, 0, r, s), w1e(w1, 2 * k + 1, 1, r, s)));
        u.w = h2_as_uint(pkrtz(w1e(w1, 2 * k + 1, 2, r, s), 0.f));
        s_w1h[threadIdx.x] = u;
    }
    if (threadIdx.x < KK) {
        const int k = threadIdx.x;
        uint4 wa;
        wa.x = h2_as_uint(pkrtz(w2[k], w2[9 + k]));
        wa.y = h2_as_uint(pkrtz(w2[18 + k], 0.f));
        wa.z = h2_as_uint(pkrtz(w2[27 + k], w2[36 + k]));
        wa.w = h2_as_uint(pkrtz(w2[45 + k], 0.f));
        s_w2a[k] = wa;
        uint2 wb;
        wb.x = h2_as_uint(pkrtz(w2[54 + k], w2[63 + k]));
        wb.y = h2_as_uint(pkrtz(w2[72 + k], 0.f));
        s_w2b[k] = wb;
    }
    if (threadIdx.x < 18) s_b[threadIdx.x] = b1[threadIdx.x];
    if (threadIdx.x < COUT) s_b2[threadIdx.x] = b2[threadIdx.x];
    __syncthreads();

    constexpr int WP = WO / 2;  // 255
    const int idx = blockIdx.x * 256 + threadIdx.x;
    if (idx >= BB * HO * WP) return;
    const int jp = idx % WP;
    const int t1 = idx / WP;
    const int i = t1 % HO;
    const int b = t1 / HO;
    const int j = jp * 2;

    const uint4* xb4 = xp + (size_t)b * (PR * PC);

    // ---- phase A: patch (pair loads) + conv1 -> packed offsets pk0/pk1 ----
    h2 p01[3][4], p2p[3][4];
#pragma unroll
    for (int r = 0; r < 3; ++r) {
        const int base = (i + r + PADR) * PC + (j + PADC);
        const uint4 qa = xb4[base];      // cols j, j+1
        const uint4 qb = xb4[base + 2];  // cols j+2, j+3
        p01[r][0] = uint_as_h2(qa.x); p2p[r][0] = uint_as_h2(qa.y);
        p01[r][1] = uint_as_h2(qa.z); p2p[r][1] = uint_as_h2(qa.w);
        p01[r][2] = uint_as_h2(qb.x); p2p[r][2] = uint_as_h2(qb.y);
        p01[r][3] = uint_as_h2(qb.z); p2p[r][3] = uint_as_h2(qb.w);
    }

    unsigned pk0[KK], pk1[KK];  // packed (dy,dx) per tap per pixel
#pragma unroll
    for (int k = 0; k < KK; ++k) {
        float dy0 = s_b[2 * k], dx0 = s_b[2 * k + 1];
        float dy1 = dy0, dx1 = dx0;
        const uint4* wk = &s_w1h[k * 9];
#pragma unroll
        for (int r = 0; r < 3; ++r)
#pragma unroll
            for (int s = 0; s < 3; ++s) {
                const uint4 wq = wk[r * 3 + s];
                const h2 wy01 = uint_as_h2(wq.x);
                const h2 wy2x = uint_as_h2(wq.y);
                const h2 wx01 = uint_as_h2(wq.z);
                const h2 wx2x = uint_as_h2(wq.w);
                dy0 = fdot2f(wy01, p01[r][s], dy0);
                dy0 = fdot2f(wy2x, p2p[r][s], dy0);
                dx0 = fdot2f(wx01, p01[r][s], dx0);
                dx0 = fdot2f(wx2x, p2p[r][s], dx0);
                dy1 = fdot2f(wy01, p01[r][s + 1], dy1);
                dy1 = fdot2f(wy2x, p2p[r][s + 1], dy1);
                dx1 = fdot2f(wx01, p01[r][s + 1], dx1);
                dx1 = fdot2f(wx2x, p2p[r][s + 1], dx1);
            }
        pk0[k] = h2_as_uint(pkrtz(dy0, dx0));
        pk1[k] = h2_as_uint(pkrtz(dy1, dx1));
    }

    // ---- phase B: pair-gather + pk-f16 bilinear + fdot2 conv2 ----
    const float fi = (float)(i + PADR);
    const float fj = (float)(j + PADC);
    float acc00 = s_b2[0], acc01 = s_b2[1], acc02 = s_b2[2];
    float acc10 = s_b2[0], acc11 = s_b2[1], acc12 = s_b2[2];

#pragma unroll
    for (int k = 0; k < KK; ++k) {
        const uint4 wa = s_w2a[k];
        const uint2 wb = s_w2b[k];
        const float ry = fi + (float)(k / 3);
        const float rx = fj + (float)(k % 3);

#pragma unroll
        for (int p = 0; p < 2; ++p) {
            const h2 d = uint_as_h2(p ? pk1[k] : pk0[k]);
            const float syp = ry + (float)d.x;             // always > 0
            const float sxp = rx + (float)p + (float)d.y;  // always > 0
            const int y0 = (int)syp;  // trunc == floor
            const int x0 = (int)sxp;
            const float fy = syp - (float)y0;
            const float fx = sxp - (float)x0;

            const int a00 = y0 * PC + x0;
            const uint4 top = xb4[a00];       // corners (y0,x0), (y0,x0+1)
            const uint4 bot = xb4[a00 + PC];  // corners (y0+1,x0), (y0+1,x0+1)

            const float wy0 = 1.f - fy, wx0 = 1.f - fx;
            const float w00 = wy0 * wx0, w01 = wy0 * fx;
            const float w10 = fy * wx0, w11 = fy * fx;
            const h2 h00 = pkrtz(w00, w00);
            const h2 h01 = pkrtz(w01, w01);
            const h2 h10 = pkrtz(w10, w10);
            const h2 h11 = pkrtz(w11, w11);

            const h2 g00 = uint_as_h2(top.x), e00 = uint_as_h2(top.y);
            const h2 g01 = uint_as_h2(top.z), e01 = uint_as_h2(top.w);
            const h2 g10 = uint_as_h2(bot.x), e10 = uint_as_h2(bot.y);
            const h2 g11 = uint_as_h2(bot.z), e11 = uint_as_h2(bot.w);

            h2 vg = h00 * g00;
            vg = h01 * g01 + vg;
            vg = h10 * g10 + vg;
            vg = h11 * g11 + vg;
            h2 ve = h00 * e00;
            ve = h01 * e01 + ve;
            ve = h10 * e10 + ve;
            ve = h11 * e11 + ve;

            if (p == 0) {
                acc00 = fdot2f(uint_as_h2(wa.x), vg, fdot2f(uint_as_h2(wa.y), ve, acc00));
                acc01 = fdot2f(uint_as_h2(wa.z), vg, fdot2f(uint_as_h2(wa.w), ve, acc01));
                acc02 = fdot2f(uint_as_h2(wb.x), vg, fdot2f(uint_as_h2(wb.y), ve, acc02));
            } else {
                acc10 = fdot2f(uint_as_h2(wa.x), vg, fdot2f(uint_as_h2(wa.y), ve, acc10));
                acc11 = fdot2f(uint_as_h2(wa.z), vg, fdot2f(uint_as_h2(wa.w), ve, acc11));
                acc12 = fdot2f(uint_as_h2(wb.x), vg, fdot2f(uint_as_h2(wb.y), ve, acc12));
            }
        }
    }

    float* ob = out + (size_t)b * COUT * HOWO + (size_t)i * WO + j;
    {
        float2 st;
        st.x = acc00; st.y = acc10;
        *reinterpret_cast<float2*>(&ob[0 * HOWO]) = st;
        st.x = acc01; st.y = acc11;
        *reinterpret_cast<float2*>(&ob[1 * HOWO]) = st;
        st.x = acc02; st.y = acc12;
        *reinterpret_cast<float2*>(&ob[2 * HOWO]) = st;
    }
}

// ---------------- fallback: R0-style fully fused (no workspace) ----------
__global__ __launch_bounds__(256) void deform_fused_kernel(
    const float* __restrict__ x, const float* __restrict__ w1,
    const float* __restrict__ b1, const float* __restrict__ w2,
    const float* __restrict__ b2, float* __restrict__ out)
{
    __shared__ float s_w1[18 * 27];
    __shared__ float s_b1[18];
    __shared__ float s_w2[COUT * CIN * KK];
    __shared__ float s_b2[COUT];
    for (int t = threadIdx.x; t < 18 * 27; t += blockDim.x) s_w1[t] = w1[t];
    if (threadIdx.x < 18) s_b1[threadIdx.x] = b1[threadIdx.x];
    if (threadIdx.x < COUT * CIN * KK) s_w2[threadIdx.x] = w2[threadIdx.x];
    if (threadIdx.x < COUT) s_b2[threadIdx.x] = b2[threadIdx.x];
    __syncthreads();
    const int idx = blockIdx.x * blockDim.x + threadIdx.x;
    if (idx >= BB * HOWO) return;
    const int j = idx % WO;
    const int tmp = idx / WO;
    const int i = tmp % HO;
    const int b = tmp / HO;
    const float* xb = x + (size_t)b * CIN * HW;
    float patch[CIN][3][3];
#pragma unroll
    for (int c = 0; c < CIN; ++c)
#pragma unroll
        for (int r = 0; r < 3; ++r)
#pragma unroll
            for (int s = 0; s < 3; ++s)
                patch[c][r][s] = xb[c * HW + (i + r) * WW + (j + s)];
    float acc0 = s_b2[0], acc1 = s_b2[1], acc2 = s_b2[2];
#pragma unroll
    for (int k = 0; k < KK; ++k) {
        const int ky = k / 3, kx = k % 3;
        float dy = s_b1[2 * k], dx = s_b1[2 * k + 1];
        const float* wy = &s_w1[(2 * k) * 27];
        const float* wx = &s_w1[(2 * k + 1) * 27];
        int t = 0;
#pragma unroll
        for (int c = 0; c < CIN; ++c)
#pragma unroll
            for (int r = 0; r < 3; ++r)
#pragma unroll
                for (int s = 0; s < 3; ++s, ++t) {
                    const float pv = patch[c][r][s];
                    dy += pv * wy[t];
                    dx += pv * wx[t];
                }
        const float sy = (float)(i + ky) + dy;
        const float sx = (float)(j + kx) + dx;
        const float y0f = floorf(sy), x0f = floorf(sx);
        const float fy = sy - y0f, fx = sx - x0f;
        const int y0 = (int)y0f, x0 = (int)x0f;
        float v0 = 0.f, v1 = 0.f, v2 = 0.f;
#pragma unroll
        for (int cy = 0; cy < 2; ++cy) {
            const int iy = y0 + cy;
            const float wyf = cy ? fy : (1.f - fy);
            const bool vy = (iy >= 0) && (iy < HH);
            const int iyc = iy < 0 ? 0 : (iy > HH - 1 ? HH - 1 : iy);
#pragma unroll
            for (int cx = 0; cx < 2; ++cx) {
                const int ix = x0 + cx;
                const float wxf = cx ? fx : (1.f - fx);
                const bool vx = (ix >= 0) && (ix < WW);
                const int ixc = ix < 0 ? 0 : (ix > WW - 1 ? WW - 1 : ix);
                const float wgt = (vy && vx) ? (wyf * wxf) : 0.f;
                const int off = iyc * WW + ixc;
                v0 += wgt * xb[0 * HW + off];
                v1 += wgt * xb[1 * HW + off];
                v2 += wgt * xb[2 * HW + off];
            }
        }
#pragma unroll
        for (int o = 0; o < COUT; ++o) {
            const float c0 = s_w2[(o * CIN + 0) * KK + k];
            const float c1 = s_w2[(o * CIN + 1) * KK + k];
            const float c2 = s_w2[(o * CIN + 2) * KK + k];
            const float contrib = c0 * v0 + c1 * v1 + c2 * v2;
            if (o == 0) acc0 += contrib;
            else if (o == 1) acc1 += contrib;
            else acc2 += contrib;
        }
    }
    float* ob = out + (size_t)b * COUT * HOWO + (size_t)i * WO + j;
    ob[0 * HOWO] = acc0;
    ob[1 * HOWO] = acc1;
    ob[2 * HOWO] = acc2;
}

extern "C" void kernel_launch(void* const* d_in, const int* in_sizes, int n_in,
                              void* d_out, int out_size, void* d_ws, size_t ws_size,
                              hipStream_t stream) {
    const float* x  = (const float*)d_in[0];
    const float* w1 = (const float*)d_in[1];
    const float* b1 = (const float*)d_in[2];
    const float* w2 = (const float*)d_in[3];
    const float* b2 = (const float*)d_in[4];
    float* out = (float*)d_out;

    if (ws_size >= XP_BYTES) {
        uint4* xp = (uint4*)d_ws;
        {
            const int total = BB * PR * PC;
            repack_pairh<<<(total + 255) / 256, 256, 0, stream>>>(x, xp);
        }
        {
            const int total = BB * HO * (WO / 2);
            deform_fused6<<<(total + 255) / 256, 256, 0, stream>>>(
                xp, w1, b1, w2, b2, out);
        }
    } else {
        const int total = BB * HOWO;
        deform_fused_kernel<<<(total + 255) / 256, 256, 0, stream>>>(
            x, w1, b1, w2, b2, out);
    }
}

// Round 12
// 47.633 us; speedup vs baseline: 1.0280x; 1.0280x over previous
//
#include <hip/hip_runtime.h>

#define BB 4
#define CIN 3
#define HH 512
#define WW 512
#define KK 9
#define COUT 3
#define HO 510
#define WO 510
#define HW (HH * WW)
#define HOWO (HO * WO)

// padded f16 NHWC buffer: [B][PR][PC] x uint2 (c0c1, c2pad), origin (PADR, PADC)
#define PR 518
#define PC 520
#define PADR 3
#define PADC 4
#define XP_BYTES ((size_t)BB * PR * PC * sizeof(uint2))

#define TROWS 9  // LDS tile rows: padded rows i .. i+8 (supports |dy| < 3)

typedef __fp16 h2 __attribute__((ext_vector_type(2)));

__device__ __forceinline__ h2 pkrtz(float a, float b) {
    return __builtin_amdgcn_cvt_pkrtz(a, b);
}
__device__ __forceinline__ float fdot2f(h2 a, h2 b, float c) {
    return __builtin_amdgcn_fdot2(a, b, c, false);
}
__device__ __forceinline__ h2 uint_as_h2(unsigned u) {
    return __builtin_bit_cast(h2, u);
}
__device__ __forceinline__ unsigned h2_as_uint(h2 h) {
    return __builtin_bit_cast(unsigned, h);
}
// w1 element: channel ch, input channel c, kernel row r, col s
__device__ __forceinline__ float w1e(const float* w1, int ch, int c, int r, int s) {
    return w1[ch * 27 + c * 9 + r * 3 + s];
}

// ---------------- kernel 1: NCHW f32 -> padded f16 NHWC ----------------
__global__ __launch_bounds__(256) void repack_padh(
    const float* __restrict__ x, uint2* __restrict__ xp)
{
    const int idx = blockIdx.x * blockDim.x + threadIdx.x;
    const int total = BB * PR * PC;
    if (idx >= total) return;
    const int b = idx / (PR * PC);
    const int rem = idx - b * (PR * PC);
    const int y = rem / PC;
    const int xc = rem - y * PC;
    const int ys = y - PADR;
    const int xs = xc - PADC;
    uint2 v = make_uint2(0u, 0u);
    if ((unsigned)ys < (unsigned)HH && (unsigned)xs < (unsigned)WW) {
        const float* xb = x + (size_t)b * CIN * HW;
        const int p = ys * WW + xs;
        v.x = h2_as_uint(pkrtz(xb[p], xb[HW + p]));
        v.y = h2_as_uint(pkrtz(xb[2 * HW + p], 0.f));
    }
    xp[idx] = v;
}

// ---- kernel 2: one block per output row; image tile staged in LDS ----
__global__ __launch_bounds__(256) void deform_fused7(
    const uint2* __restrict__ xp,   // [B][PR][PC] padded f16 NHWC
    const float* __restrict__ w1,   // [18][3][3][3]
    const float* __restrict__ b1,   // [18]
    const float* __restrict__ w2,   // [3][3][3][3]
    const float* __restrict__ b2,   // [3]
    float* __restrict__ out)        // [B][3][HO][WO]
{
    __shared__ uint4 s_tile4[TROWS * PC / 2];  // 37.4 KB: padded rows i..i+8
    __shared__ uint4 s_w1h[KK * 9];
    __shared__ float s_b[18];
    __shared__ float s_w2[KK * 12];  // [k][12], first 9 = o*3+c
    __shared__ float s_b2[COUT];
    uint2* s_tile = reinterpret_cast<uint2*>(s_tile4);

    const int bi = blockIdx.x;
    const int b = bi / HO;
    const int i = bi - b * HO;  // output row

    // ---- stage weights ----
    if (threadIdx.x < KK * 9) {
        const int k = threadIdx.x / 9;
        const int pos = threadIdx.x % 9;
        const int r = pos / 3, s = pos % 3;
        uint4 u;
        u.x = h2_as_uint(pkrtz(w1e(w1, 2 * k, 0, r, s), w1e(w1, 2 * k, 1, r, s)));
        u.y = h2_as_uint(pkrtz(w1e(w1, 2 * k, 2, r, s), 0.f));
        u.z = h2_as_uint(pkrtz(w1e(w1, 2 * k + 1, 0, r, s), w1e(w1, 2 * k + 1, 1, r, s)));
        u.w = h2_as_uint(pkrtz(w1e(w1, 2 * k + 1, 2, r, s), 0.f));
        s_w1h[threadIdx.x] = u;
    }
    for (int t = threadIdx.x; t < KK * 12; t += 256) {
        const int k = t / 12;
        const int q = t % 12;
        s_w2[t] = (q < 9) ? w2[(q / 3) * 27 + (q % 3) * 9 + k] : 0.f;
    }
    if (threadIdx.x < 18) s_b[threadIdx.x] = b1[threadIdx.x];
    if (threadIdx.x < COUT) s_b2[threadIdx.x] = b2[threadIdx.x];

    // ---- stage image tile: padded rows i..i+8 (contiguous span) ----
    {
        const uint4* src4 = reinterpret_cast<const uint4*>(
            xp + (size_t)b * (PR * PC) + (size_t)i * PC);
        constexpr int N4 = TROWS * PC / 2;  // 2340
#pragma unroll
        for (int e = threadIdx.x; e < N4; e += 256) s_tile4[e] = src4[e];
    }
    __syncthreads();

    constexpr int WP = WO / 2;  // 255
    const int jp = threadIdx.x;
    if (jp >= WP) return;  // thread 255: staging only
    const int j = jp * 2;

    // ---- phase A: patch from LDS + conv1 -> packed offsets pk0/pk1 ----
    h2 p01[3][4], p2p[3][4];
#pragma unroll
    for (int r = 0; r < 3; ++r) {
        // image row i+r = padded row i+3+r = tile row 3+r; cols j+4..j+7
        const int base4 = (3 + r) * (PC / 2) + jp + 2;
        const uint4 qa = s_tile4[base4];
        const uint4 qb = s_tile4[base4 + 1];
        p01[r][0] = uint_as_h2(qa.x); p2p[r][0] = uint_as_h2(qa.y);
        p01[r][1] = uint_as_h2(qa.z); p2p[r][1] = uint_as_h2(qa.w);
        p01[r][2] = uint_as_h2(qb.x); p2p[r][2] = uint_as_h2(qb.y);
        p01[r][3] = uint_as_h2(qb.z); p2p[r][3] = uint_as_h2(qb.w);
    }

    unsigned pk0[KK], pk1[KK];
#pragma unroll
    for (int k = 0; k < KK; ++k) {
        float dy0 = s_b[2 * k], dx0 = s_b[2 * k + 1];
        float dy1 = dy0, dx1 = dx0;
        const uint4* wk = &s_w1h[k * 9];
#pragma unroll
        for (int r = 0; r < 3; ++r)
#pragma unroll
            for (int s = 0; s < 3; ++s) {
                const uint4 wq = wk[r * 3 + s];
                const h2 wy01 = uint_as_h2(wq.x);
                const h2 wy2x = uint_as_h2(wq.y);
                const h2 wx01 = uint_as_h2(wq.z);
                const h2 wx2x = uint_as_h2(wq.w);
                dy0 = fdot2f(wy01, p01[r][s], dy0);
                dy0 = fdot2f(wy2x, p2p[r][s], dy0);
                dx0 = fdot2f(wx01, p01[r][s], dx0);
                dx0 = fdot2f(wx2x, p2p[r][s], dx0);
                dy1 = fdot2f(wy01, p01[r][s + 1], dy1);
                dy1 = fdot2f(wy2x, p2p[r][s + 1], dy1);
                dx1 = fdot2f(wx01, p01[r][s + 1], dx1);
                dx1 = fdot2f(wx2x, p2p[r][s + 1], dx1);
            }
        pk0[k] = h2_as_uint(pkrtz(dy0, dx0));
        pk1[k] = h2_as_uint(pkrtz(dy1, dx1));
    }

    // ---- phase B: gather from LDS + bilinear (f32) + conv2 ----
    const float fi = (float)(i + PADR);
    const float fj = (float)(j + PADC);
    float acc00 = s_b2[0], acc01 = s_b2[1], acc02 = s_b2[2];
    float acc10 = s_b2[0], acc11 = s_b2[1], acc12 = s_b2[2];

#pragma unroll
    for (int k = 0; k < KK; ++k) {
        const float4* wk4 = reinterpret_cast<const float4*>(&s_w2[k * 12]);
        const float4 a = wk4[0];
        const float4 bbv = wk4[1];
        const float cw = s_w2[k * 12 + 8];
        const float ry = fi + (float)(k / 3);
        const float rx = fj + (float)(k % 3);

#pragma unroll
        for (int p = 0; p < 2; ++p) {
            const h2 d = uint_as_h2(p ? pk1[k] : pk0[k]);
            const float syp = ry + (float)d.x;             // padded row coord
            const float sxp = rx + (float)p + (float)d.y;  // padded col coord
            const int y0 = (int)syp;  // trunc == floor (always > 0)
            const int x0 = (int)sxp;
            const float fy = syp - (float)y0;
            const float fx = sxp - (float)x0;

            const int ly = y0 - i;  // tile row in [0, 7]; +1 row below
            const int a00 = ly * PC + x0;
            const uint2 c00 = s_tile[a00];
            const uint2 c01 = s_tile[a00 + 1];
            const uint2 c10 = s_tile[a00 + PC];
            const uint2 c11 = s_tile[a00 + PC + 1];

            const float wy0 = 1.f - fy, wx0 = 1.f - fx;
            const float w00 = wy0 * wx0, w01 = wy0 * fx;
            const float w10 = fy * wx0, w11 = fy * fx;

            const h2 g00 = uint_as_h2(c00.x), e00 = uint_as_h2(c00.y);
            const h2 g01 = uint_as_h2(c01.x), e01 = uint_as_h2(c01.y);
            const h2 g10 = uint_as_h2(c10.x), e10 = uint_as_h2(c10.y);
            const h2 g11 = uint_as_h2(c11.x), e11 = uint_as_h2(c11.y);

            const float v0 = w00 * (float)g00.x + w01 * (float)g01.x +
                             w10 * (float)g10.x + w11 * (float)g11.x;
            const float v1 = w00 * (float)g00.y + w01 * (float)g01.y +
                             w10 * (float)g10.y + w11 * (float)g11.y;
            const float v2 = w00 * (float)e00.x + w01 * (float)e01.x +
                             w10 * (float)e10.x + w11 * (float)e11.x;

            const float r0 = a.x * v0 + a.y * v1 + a.z * v2;
            const float r1 = a.w * v0 + bbv.x * v1 + bbv.y * v2;
            const float r2 = bbv.z * v0 + bbv.w * v1 + cw * v2;
            if (p == 0) {
                acc00 += r0; acc01 += r1; acc02 += r2;
            } else {
                acc10 += r0; acc11 += r1; acc12 += r2;
            }
        }
    }

    float* ob = out + (size_t)b * COUT * HOWO + (size_t)i * WO + j;
    {
        float2 st;
        st.x = acc00; st.y = acc10;
        *reinterpret_cast<float2*>(&ob[0 * HOWO]) = st;
        st.x = acc01; st.y = acc11;
        *reinterpret_cast<float2*>(&ob[1 * HOWO]) = st;
        st.x = acc02; st.y = acc12;
        *reinterpret_cast<float2*>(&ob[2 * HOWO]) = st;
    }
}

// ---------------- fallback: R0-style fully fused (no workspace) ----------
__global__ __launch_bounds__(256) void deform_fused_kernel(
    const float* __restrict__ x, const float* __restrict__ w1,
    const float* __restrict__ b1, const float* __restrict__ w2,
    const float* __restrict__ b2, float* __restrict__ out)
{
    __shared__ float s_w1[18 * 27];
    __shared__ float s_b1[18];
    __shared__ float s_w2[COUT * CIN * KK];
    __shared__ float s_b2[COUT];
    for (int t = threadIdx.x; t < 18 * 27; t += blockDim.x) s_w1[t] = w1[t];
    if (threadIdx.x < 18) s_b1[threadIdx.x] = b1[threadIdx.x];
    if (threadIdx.x < COUT * CIN * KK) s_w2[threadIdx.x] = w2[threadIdx.x];
    if (threadIdx.x < COUT) s_b2[threadIdx.x] = b2[threadIdx.x];
    __syncthreads();
    const int idx = blockIdx.x * blockDim.x + threadIdx.x;
    if (idx >= BB * HOWO) return;
    const int j = idx % WO;
    const int tmp = idx / WO;
    const int i = tmp % HO;
    const int b = tmp / HO;
    const float* xb = x + (size_t)b * CIN * HW;
    float patch[CIN][3][3];
#pragma unroll
    for (int c = 0; c < CIN; ++c)
#pragma unroll
        for (int r = 0; r < 3; ++r)
#pragma unroll
            for (int s = 0; s < 3; ++s)
                patch[c][r][s] = xb[c * HW + (i + r) * WW + (j + s)];
    float acc0 = s_b2[0], acc1 = s_b2[1], acc2 = s_b2[2];
#pragma unroll
    for (int k = 0; k < KK; ++k) {
        const int ky = k / 3, kx = k % 3;
        float dy = s_b1[2 * k], dx = s_b1[2 * k + 1];
        const float* wy = &s_w1[(2 * k) * 27];
        const float* wx = &s_w1[(2 * k + 1) * 27];
        int t = 0;
#pragma unroll
        for (int c = 0; c < CIN; ++c)
#pragma unroll
            for (int r = 0; r < 3; ++r)
#pragma unroll
                for (int s = 0; s < 3; ++s, ++t) {
                    const float pv = patch[c][r][s];
                    dy += pv * wy[t];
                    dx += pv * wx[t];
                }
        const float sy = (float)(i + ky) + dy;
        const float sx = (float)(j + kx) + dx;
        const float y0f = floorf(sy), x0f = floorf(sx);
        const float fy = sy - y0f, fx = sx - x0f;
        const int y0 = (int)y0f, x0 = (int)x0f;
        float v0 = 0.f, v1 = 0.f, v2 = 0.f;
#pragma unroll
        for (int cy = 0; cy < 2; ++cy) {
            const int iy = y0 + cy;
            const float wyf = cy ? fy : (1.f - fy);
            const bool vy = (iy >= 0) && (iy < HH);
            const int iyc = iy < 0 ? 0 : (iy > HH - 1 ? HH - 1 : iy);
#pragma unroll
            for (int cx = 0; cx < 2; ++cx) {
                const int ix = x0 + cx;
                const float wxf = cx ? fx : (1.f - fx);
                const bool vx = (ix >= 0) && (ix < WW);
                const int ixc = ix < 0 ? 0 : (ix > WW - 1 ? WW - 1 : ix);
                const float wgt = (vy && vx) ? (wyf * wxf) : 0.f;
                const int off = iyc * WW + ixc;
                v0 += wgt * xb[0 * HW + off];
                v1 += wgt * xb[1 * HW + off];
                v2 += wgt * xb[2 * HW + off];
            }
        }
#pragma unroll
        for (int o = 0; o < COUT; ++o) {
            const float c0 = s_w2[(o * CIN + 0) * KK + k];
            const float c1 = s_w2[(o * CIN + 1) * KK + k];
            const float c2 = s_w2[(o * CIN + 2) * KK + k];
            const float contrib = c0 * v0 + c1 * v1 + c2 * v2;
            if (o == 0) acc0 += contrib;
            else if (o == 1) acc1 += contrib;
            else acc2 += contrib;
        }
    }
    float* ob = out + (size_t)b * COUT * HOWO + (size_t)i * WO + j;
    ob[0 * HOWO] = acc0;
    ob[1 * HOWO] = acc1;
    ob[2 * HOWO] = acc2;
}

extern "C" void kernel_launch(void* const* d_in, const int* in_sizes, int n_in,
                              void* d_out, int out_size, void* d_ws, size_t ws_size,
                              hipStream_t stream) {
    const float* x  = (const float*)d_in[0];
    const float* w1 = (const float*)d_in[1];
    const float* b1 = (const float*)d_in[2];
    const float* w2 = (const float*)d_in[3];
    const float* b2 = (const float*)d_in[4];
    float* out = (float*)d_out;

    if (ws_size >= XP_BYTES) {
        uint2* xp = (uint2*)d_ws;
        {
            const int total = BB * PR * PC;
            repack_padh<<<(total + 255) / 256, 256, 0, stream>>>(x, xp);
        }
        {
            deform_fused7<<<BB * HO, 256, 0, stream>>>(xp, w1, b1, w2, b2, out);
        }
    } else {
        const int total = BB * HOWO;
        deform_fused_kernel<<<(total + 255) / 256, 256, 0, stream>>>(
            x, w1, b1, w2, b2, out);
    }
}

// Round 13
// 39.674 us; speedup vs baseline: 1.2343x; 1.2006x over previous
//
#include <hip/hip_runtime.h>

#define BB 4
#define CIN 3
#define HH 512
#define WW 512
#define KK 9
#define COUT 3
#define HO 510
#define WO 510
#define HW (HH * WW)
#define HOWO (HO * WO)

// padded f16 NHWC buffer: [B][PR][PC] x uint2 (c0c1, c2pad), origin (PADR, PADC)
#define PR 518
#define PC 520
#define PADR 3
#define PADC 4
#define XP_BYTES ((size_t)BB * PR * PC * sizeof(uint2))

typedef __fp16 h2 __attribute__((ext_vector_type(2)));

__device__ __forceinline__ h2 pkrtz(float a, float b) {
    return __builtin_amdgcn_cvt_pkrtz(a, b);
}
__device__ __forceinline__ float fdot2f(h2 a, h2 b, float c) {
    return __builtin_amdgcn_fdot2(a, b, c, false);
}
__device__ __forceinline__ h2 uint_as_h2(unsigned u) {
    return __builtin_bit_cast(h2, u);
}
__device__ __forceinline__ unsigned h2_as_uint(h2 h) {
    return __builtin_bit_cast(unsigned, h);
}
// w1 element: channel ch, input channel c, kernel row r, col s
__device__ __forceinline__ float w1e(const float* w1, int ch, int c, int r, int s) {
    return w1[ch * 27 + c * 9 + r * 3 + s];
}

// ---------------- kernel 1: NCHW f32 -> padded f16 NHWC ----------------
__global__ __launch_bounds__(256) void repack_padh(
    const float* __restrict__ x, uint2* __restrict__ xp)
{
    const int idx = blockIdx.x * blockDim.x + threadIdx.x;
    const int total = BB * PR * PC;
    if (idx >= total) return;
    const int b = idx / (PR * PC);
    const int rem = idx - b * (PR * PC);
    const int y = rem / PC;
    const int xc = rem - y * PC;
    const int ys = y - PADR;
    const int xs = xc - PADC;
    uint2 v = make_uint2(0u, 0u);
    if ((unsigned)ys < (unsigned)HH && (unsigned)xs < (unsigned)WW) {
        const float* xb = x + (size_t)b * CIN * HW;
        const int p = ys * WW + xs;
        v.x = h2_as_uint(pkrtz(xb[p], xb[HW + p]));
        v.y = h2_as_uint(pkrtz(xb[2 * HW + p], 0.f));
    }
    xp[idx] = v;
}

// -- kernel 2: R10 structure + packed-f16 bilinear/conv2 (isolated change) --
__global__ __launch_bounds__(256) void deform_fused8(
    const uint2* __restrict__ xp,   // [B][PR][PC] padded f16 NHWC
    const float* __restrict__ w1,   // [18][3][3][3]
    const float* __restrict__ b1,   // [18]
    const float* __restrict__ w2,   // [3][3][3][3]
    const float* __restrict__ b2,   // [3]
    float* __restrict__ out)        // [B][3][HO][WO]
{
    // conv1 weights: s_w1h[k*9+pos] = {wy_c01, wy_c2x, wx_c01, wx_c2x}
    __shared__ uint4 s_w1h[KK * 9];
    __shared__ float s_b[18];
    // conv2 weights packed h2: per tap k, wa = {o0_c01,o0_c2x,o1_c01,o1_c2x},
    // wb = {o2_c01, o2_c2x}
    __shared__ uint4 s_w2a[KK];
    __shared__ uint2 s_w2b[KK];
    __shared__ float s_b2[COUT];

    if (threadIdx.x < KK * 9) {
        const int k = threadIdx.x / 9;
        const int pos = threadIdx.x % 9;
        const int r = pos / 3, s = pos % 3;
        uint4 u;
        u.x = h2_as_uint(pkrtz(w1e(w1, 2 * k, 0, r, s), w1e(w1, 2 * k, 1, r, s)));
        u.y = h2_as_uint(pkrtz(w1e(w1, 2 * k, 2, r, s), 0.f));
        u.z = h2_as_uint(pkrtz(w1e(w1, 2 * k + 1, 0, r, s), w1e(w1, 2 * k + 1, 1, r, s)));
        u.w = h2_as_uint(pkrtz(w1e(w1, 2 * k + 1, 2, r, s), 0.f));
        s_w1h[threadIdx.x] = u;
    }
    if (threadIdx.x < KK) {
        const int k = threadIdx.x;
        uint4 wa;
        wa.x = h2_as_uint(pkrtz(w2[k], w2[9 + k]));
        wa.y = h2_as_uint(pkrtz(w2[18 + k], 0.f));
        wa.z = h2_as_uint(pkrtz(w2[27 + k], w2[36 + k]));
        wa.w = h2_as_uint(pkrtz(w2[45 + k], 0.f));
        s_w2a[k] = wa;
        uint2 wb;
        wb.x = h2_as_uint(pkrtz(w2[54 + k], w2[63 + k]));
        wb.y = h2_as_uint(pkrtz(w2[72 + k], 0.f));
        s_w2b[k] = wb;
    }
    if (threadIdx.x < 18) s_b[threadIdx.x] = b1[threadIdx.x];
    if (threadIdx.x < COUT) s_b2[threadIdx.x] = b2[threadIdx.x];
    __syncthreads();

    constexpr int WP = WO / 2;  // 255
    const int idx = blockIdx.x * 256 + threadIdx.x;
    if (idx >= BB * HO * WP) return;
    const int jp = idx % WP;
    const int t1 = idx / WP;
    const int i = t1 % HO;
    const int b = t1 / HO;
    const int j = jp * 2;

    const uint2* xb2 = xp + (size_t)b * (PR * PC);

    // ---- phase A: patch (f16 native) + conv1 -> packed offsets pk0/pk1 ----
    h2 p01[3][4], p2p[3][4];
#pragma unroll
    for (int r = 0; r < 3; ++r) {
        const int base = (i + r + PADR) * PC + (j + PADC);  // even elem idx
        const uint4 qa = *reinterpret_cast<const uint4*>(xb2 + base);
        const uint4 qb = *reinterpret_cast<const uint4*>(xb2 + base + 2);
        p01[r][0] = uint_as_h2(qa.x); p2p[r][0] = uint_as_h2(qa.y);
        p01[r][1] = uint_as_h2(qa.z); p2p[r][1] = uint_as_h2(qa.w);
        p01[r][2] = uint_as_h2(qb.x); p2p[r][2] = uint_as_h2(qb.y);
        p01[r][3] = uint_as_h2(qb.z); p2p[r][3] = uint_as_h2(qb.w);
    }

    unsigned pk0[KK], pk1[KK];  // packed (dy,dx) per tap per pixel
#pragma unroll
    for (int k = 0; k < KK; ++k) {
        float dy0 = s_b[2 * k], dx0 = s_b[2 * k + 1];
        float dy1 = dy0, dx1 = dx0;
        const uint4* wk = &s_w1h[k * 9];
#pragma unroll
        for (int r = 0; r < 3; ++r)
#pragma unroll
            for (int s = 0; s < 3; ++s) {
                const uint4 wq = wk[r * 3 + s];
                const h2 wy01 = uint_as_h2(wq.x);
                const h2 wy2x = uint_as_h2(wq.y);
                const h2 wx01 = uint_as_h2(wq.z);
                const h2 wx2x = uint_as_h2(wq.w);
                dy0 = fdot2f(wy01, p01[r][s], dy0);
                dy0 = fdot2f(wy2x, p2p[r][s], dy0);
                dx0 = fdot2f(wx01, p01[r][s], dx0);
                dx0 = fdot2f(wx2x, p2p[r][s], dx0);
                dy1 = fdot2f(wy01, p01[r][s + 1], dy1);
                dy1 = fdot2f(wy2x, p2p[r][s + 1], dy1);
                dx1 = fdot2f(wx01, p01[r][s + 1], dx1);
                dx1 = fdot2f(wx2x, p2p[r][s + 1], dx1);
            }
        pk0[k] = h2_as_uint(pkrtz(dy0, dx0));
        pk1[k] = h2_as_uint(pkrtz(dy1, dx1));
    }

    // ---- phase B: uint2 gather + pk-f16 bilinear + fdot2 conv2 ----
    const float fi = (float)(i + PADR);
    const float fj = (float)(j + PADC);
    float acc00 = s_b2[0], acc01 = s_b2[1], acc02 = s_b2[2];
    float acc10 = s_b2[0], acc11 = s_b2[1], acc12 = s_b2[2];

#pragma unroll
    for (int k = 0; k < KK; ++k) {
        const uint4 wa = s_w2a[k];
        const uint2 wb = s_w2b[k];
        const float ry = fi + (float)(k / 3);
        const float rx = fj + (float)(k % 3);

#pragma unroll
        for (int p = 0; p < 2; ++p) {
            const h2 d = uint_as_h2(p ? pk1[k] : pk0[k]);
            const float syp = ry + (float)d.x;             // always > 0
            const float sxp = rx + (float)p + (float)d.y;  // always > 0
            const int y0 = (int)syp;  // trunc == floor
            const int x0 = (int)sxp;
            const float fy = syp - (float)y0;
            const float fx = sxp - (float)x0;

            const int a00 = y0 * PC + x0;
            const uint2 c00 = xb2[a00];
            const uint2 c01 = xb2[a00 + 1];
            const uint2 c10 = xb2[a00 + PC];
            const uint2 c11 = xb2[a00 + PC + 1];

            const float wy0 = 1.f - fy, wx0 = 1.f - fx;
            const float w00 = wy0 * wx0, w01 = wy0 * fx;
            const float w10 = fy * wx0, w11 = fy * fx;
            const h2 h00 = pkrtz(w00, w00);
            const h2 h01 = pkrtz(w01, w01);
            const h2 h10 = pkrtz(w10, w10);
            const h2 h11 = pkrtz(w11, w11);

            const h2 g00 = uint_as_h2(c00.x), e00 = uint_as_h2(c00.y);
            const h2 g01 = uint_as_h2(c01.x), e01 = uint_as_h2(c01.y);
            const h2 g10 = uint_as_h2(c10.x), e10 = uint_as_h2(c10.y);
            const h2 g11 = uint_as_h2(c11.x), e11 = uint_as_h2(c11.y);

            h2 vg = h00 * g00;
            vg = h01 * g01 + vg;
            vg = h10 * g10 + vg;
            vg = h11 * g11 + vg;
            h2 ve = h00 * e00;
            ve = h01 * e01 + ve;
            ve = h10 * e10 + ve;
            ve = h11 * e11 + ve;

            if (p == 0) {
                acc00 = fdot2f(uint_as_h2(wa.x), vg, fdot2f(uint_as_h2(wa.y), ve, acc00));
                acc01 = fdot2f(uint_as_h2(wa.z), vg, fdot2f(uint_as_h2(wa.w), ve, acc01));
                acc02 = fdot2f(uint_as_h2(wb.x), vg, fdot2f(uint_as_h2(wb.y), ve, acc02));
            } else {
                acc10 = fdot2f(uint_as_h2(wa.x), vg, fdot2f(uint_as_h2(wa.y), ve, acc10));
                acc11 = fdot2f(uint_as_h2(wa.z), vg, fdot2f(uint_as_h2(wa.w), ve, acc11));
                acc12 = fdot2f(uint_as_h2(wb.x), vg, fdot2f(uint_as_h2(wb.y), ve, acc12));
            }
        }
    }

    float* ob = out + (size_t)b * COUT * HOWO + (size_t)i * WO + j;
    {
        float2 st;
        st.x = acc00; st.y = acc10;
        *reinterpret_cast<float2*>(&ob[0 * HOWO]) = st;
        st.x = acc01; st.y = acc11;
        *reinterpret_cast<float2*>(&ob[1 * HOWO]) = st;
        st.x = acc02; st.y = acc12;
        *reinterpret_cast<float2*>(&ob[2 * HOWO]) = st;
    }
}

// ---------------- fallback: R0-style fully fused (no workspace) ----------
__global__ __launch_bounds__(256) void deform_fused_kernel(
    const float* __restrict__ x, const float* __restrict__ w1,
    const float* __restrict__ b1, const float* __restrict__ w2,
    const float* __restrict__ b2, float* __restrict__ out)
{
    __shared__ float s_w1[18 * 27];
    __shared__ float s_b1[18];
    __shared__ float s_w2[COUT * CIN * KK];
    __shared__ float s_b2[COUT];
    for (int t = threadIdx.x; t < 18 * 27; t += blockDim.x) s_w1[t] = w1[t];
    if (threadIdx.x < 18) s_b1[threadIdx.x] = b1[threadIdx.x];
    if (threadIdx.x < COUT * CIN * KK) s_w2[threadIdx.x] = w2[threadIdx.x];
    if (threadIdx.x < COUT) s_b2[threadIdx.x] = b2[threadIdx.x];
    __syncthreads();
    const int idx = blockIdx.x * blockDim.x + threadIdx.x;
    if (idx >= BB * HOWO) return;
    const int j = idx % WO;
    const int tmp = idx / WO;
    const int i = tmp % HO;
    const int b = tmp / HO;
    const float* xb = x + (size_t)b * CIN * HW;
    float patch[CIN][3][3];
#pragma unroll
    for (int c = 0; c < CIN; ++c)
#pragma unroll
        for (int r = 0; r < 3; ++r)
#pragma unroll
            for (int s = 0; s < 3; ++s)
                patch[c][r][s] = xb[c * HW + (i + r) * WW + (j + s)];
    float acc0 = s_b2[0], acc1 = s_b2[1], acc2 = s_b2[2];
#pragma unroll
    for (int k = 0; k < KK; ++k) {
        const int ky = k / 3, kx = k % 3;
        float dy = s_b1[2 * k], dx = s_b1[2 * k + 1];
        const float* wy = &s_w1[(2 * k) * 27];
        const float* wx = &s_w1[(2 * k + 1) * 27];
        int t = 0;
#pragma unroll
        for (int c = 0; c < CIN; ++c)
#pragma unroll
            for (int r = 0; r < 3; ++r)
#pragma unroll
                for (int s = 0; s < 3; ++s, ++t) {
                    const float pv = patch[c][r][s];
                    dy += pv * wy[t];
                    dx += pv * wx[t];
                }
        const float sy = (float)(i + ky) + dy;
        const float sx = (float)(j + kx) + dx;
        const float y0f = floorf(sy), x0f = floorf(sx);
        const float fy = sy - y0f, fx = sx - x0f;
        const int y0 = (int)y0f, x0 = (int)x0f;
        float v0 = 0.f, v1 = 0.f, v2 = 0.f;
#pragma unroll
        for (int cy = 0; cy < 2; ++cy) {
            const int iy = y0 + cy;
            const float wyf = cy ? fy : (1.f - fy);
            const bool vy = (iy >= 0) && (iy < HH);
            const int iyc = iy < 0 ? 0 : (iy > HH - 1 ? HH - 1 : iy);
#pragma unroll
            for (int cx = 0; cx < 2; ++cx) {
                const int ix = x0 + cx;
                const float wxf = cx ? fx : (1.f - fx);
                const bool vx = (ix >= 0) && (ix < WW);
                const int ixc = ix < 0 ? 0 : (ix > WW - 1 ? WW - 1 : ix);
                const float wgt = (vy && vx) ? (wyf * wxf) : 0.f;
                const int off = iyc * WW + ixc;
                v0 += wgt * xb[0 * HW + off];
                v1 += wgt * xb[1 * HW + off];
                v2 += wgt * xb[2 * HW + off];
            }
        }
#pragma unroll
        for (int o = 0; o < COUT; ++o) {
            const float c0 = s_w2[(o * CIN + 0) * KK + k];
            const float c1 = s_w2[(o * CIN + 1) * KK + k];
            const float c2 = s_w2[(o * CIN + 2) * KK + k];
            const float contrib = c0 * v0 + c1 * v1 + c2 * v2;
            if (o == 0) acc0 += contrib;
            else if (o == 1) acc1 += contrib;
            else acc2 += contrib;
        }
    }
    float* ob = out + (size_t)b * COUT * HOWO + (size_t)i * WO + j;
    ob[0 * HOWO] = acc0;
    ob[1 * HOWO] = acc1;
    ob[2 * HOWO] = acc2;
}

extern "C" void kernel_launch(void* const* d_in, const int* in_sizes, int n_in,
                              void* d_out, int out_size, void* d_ws, size_t ws_size,
                              hipStream_t stream) {
    const float* x  = (const float*)d_in[0];
    const float* w1 = (const float*)d_in[1];
    const float* b1 = (const float*)d_in[2];
    const float* w2 = (const float*)d_in[3];
    const float* b2 = (const float*)d_in[4];
    float* out = (float*)d_out;

    if (ws_size >= XP_BYTES) {
        uint2* xp = (uint2*)d_ws;
        {
            const int total = BB * PR * PC;
            repack_padh<<<(total + 255) / 256, 256, 0, stream>>>(x, xp);
        }
        {
            const int total = BB * HO * (WO / 2);
            deform_fused8<<<(total + 255) / 256, 256, 0, stream>>>(
                xp, w1, b1, w2, b2, out);
        }
    } else {
        const int total = BB * HOWO;
        deform_fused_kernel<<<(total + 255) / 256, 256, 0, stream>>>(
            x, w1, b1, w2, b2, out);
    }
}

// Round 14
// 38.838 us; speedup vs baseline: 1.2608x; 1.0215x over previous
//
#include <hip/hip_runtime.h>

#define BB 4
#define CIN 3
#define HH 512
#define WW 512
#define KK 9
#define COUT 3
#define HO 510
#define WO 510
#define HW (HH * WW)
#define HOWO (HO * WO)

// padded f16 NHWC buffer: [B][PR][PC] x uint2 (c0c1, c2pad), origin (PADR, PADC)
#define PR 518
#define PC 520
#define PADR 3
#define PADC 4
#define XP_BYTES ((size_t)BB * PR * PC * sizeof(uint2))

typedef __fp16 h2 __attribute__((ext_vector_type(2)));

__device__ __forceinline__ h2 pkrtz(float a, float b) {
    return __builtin_amdgcn_cvt_pkrtz(a, b);
}
__device__ __forceinline__ float fdot2f(h2 a, h2 b, float c) {
    return __builtin_amdgcn_fdot2(a, b, c, false);
}
__device__ __forceinline__ h2 uint_as_h2(unsigned u) {
    return __builtin_bit_cast(h2, u);
}
__device__ __forceinline__ unsigned h2_as_uint(h2 h) {
    return __builtin_bit_cast(unsigned, h);
}
// w1 element: channel ch, input channel c, kernel row r, col s
__device__ __forceinline__ float w1e(const float* w1, int ch, int c, int r, int s) {
    return w1[ch * 27 + c * 9 + r * 3 + s];
}

// ------------- kernel 1: NCHW f32 -> padded f16 NHWC, 2 px/thread -----------
__global__ __launch_bounds__(256) void repack_padh2(
    const float* __restrict__ x, uint2* __restrict__ xp)
{
    constexpr int PCH = PC / 2;  // 260 column-pairs
    const int idx = blockIdx.x * blockDim.x + threadIdx.x;
    const int total = BB * PR * PCH;
    if (idx >= total) return;
    const int b = idx / (PR * PCH);
    const int rem = idx - b * (PR * PCH);
    const int y = rem / PCH;
    const int q = rem - y * PCH;
    const int ys = y - PADR;
    const int xs = 2 * q - PADC;  // even; pair is all-or-nothing valid
    uint4 v = make_uint4(0u, 0u, 0u, 0u);
    if ((unsigned)ys < (unsigned)HH && (unsigned)xs < (unsigned)WW) {
        const float* xb = x + (size_t)b * CIN * HW;
        const int p = ys * WW + xs;
        const float2 a0 = *reinterpret_cast<const float2*>(xb + p);
        const float2 a1 = *reinterpret_cast<const float2*>(xb + HW + p);
        const float2 a2 = *reinterpret_cast<const float2*>(xb + 2 * HW + p);
        v.x = h2_as_uint(pkrtz(a0.x, a1.x));
        v.y = h2_as_uint(pkrtz(a2.x, 0.f));
        v.z = h2_as_uint(pkrtz(a0.y, a1.y));
        v.w = h2_as_uint(pkrtz(a2.y, 0.f));
    }
    reinterpret_cast<uint4*>(xp)[idx] = v;
}

// -------- kernel 2: fused, 1 px/thread (minimal state, max waves) ----------
__global__ __launch_bounds__(256) void deform_fused9(
    const uint2* __restrict__ xp,   // [B][PR][PC] padded f16 NHWC
    const float* __restrict__ w1,   // [18][3][3][3]
    const float* __restrict__ b1,   // [18]
    const float* __restrict__ w2,   // [3][3][3][3]
    const float* __restrict__ b2,   // [3]
    float* __restrict__ out)        // [B][3][HO][WO]
{
    // conv1 weights: s_w1h[k*9+pos] = {wy_c01, wy_c2x, wx_c01, wx_c2x}
    __shared__ uint4 s_w1h[KK * 9];
    __shared__ float s_b[18];
    // conv2 weights packed h2: per tap k, wa = {o0_c01,o0_c2x,o1_c01,o1_c2x},
    // wb = {o2_c01, o2_c2x}
    __shared__ uint4 s_w2a[KK];
    __shared__ uint2 s_w2b[KK];
    __shared__ float s_b2[COUT];

    if (threadIdx.x < KK * 9) {
        const int k = threadIdx.x / 9;
        const int pos = threadIdx.x % 9;
        const int r = pos / 3, s = pos % 3;
        uint4 u;
        u.x = h2_as_uint(pkrtz(w1e(w1, 2 * k, 0, r, s), w1e(w1, 2 * k, 1, r, s)));
        u.y = h2_as_uint(pkrtz(w1e(w1, 2 * k, 2, r, s), 0.f));
        u.z = h2_as_uint(pkrtz(w1e(w1, 2 * k + 1, 0, r, s), w1e(w1, 2 * k + 1, 1, r, s)));
        u.w = h2_as_uint(pkrtz(w1e(w1, 2 * k + 1, 2, r, s), 0.f));
        s_w1h[threadIdx.x] = u;
    }
    if (threadIdx.x < KK) {
        const int k = threadIdx.x;
        uint4 wa;
        wa.x = h2_as_uint(pkrtz(w2[k], w2[9 + k]));
        wa.y = h2_as_uint(pkrtz(w2[18 + k], 0.f));
        wa.z = h2_as_uint(pkrtz(w2[27 + k], w2[36 + k]));
        wa.w = h2_as_uint(pkrtz(w2[45 + k], 0.f));
        s_w2a[k] = wa;
        uint2 wb;
        wb.x = h2_as_uint(pkrtz(w2[54 + k], w2[63 + k]));
        wb.y = h2_as_uint(pkrtz(w2[72 + k], 0.f));
        s_w2b[k] = wb;
    }
    if (threadIdx.x < 18) s_b[threadIdx.x] = b1[threadIdx.x];
    if (threadIdx.x < COUT) s_b2[threadIdx.x] = b2[threadIdx.x];
    __syncthreads();

    const int idx = blockIdx.x * 256 + threadIdx.x;
    if (idx >= BB * HOWO) return;
    const int j = idx % WO;
    const int t1 = idx / WO;
    const int i = t1 % HO;
    const int b = t1 / HO;

    const uint2* xb2 = xp + (size_t)b * (PR * PC);

    // ---- phase A: 3x3 patch (9 uint2 loads) + conv1 -> packed offsets ----
    h2 p01[3][3], p2p[3][3];
#pragma unroll
    for (int r = 0; r < 3; ++r)
#pragma unroll
        for (int s = 0; s < 3; ++s) {
            const uint2 q = xb2[(i + r + PADR) * PC + (j + s + PADC)];
            p01[r][s] = uint_as_h2(q.x);
            p2p[r][s] = uint_as_h2(q.y);
        }

    unsigned pk[KK];
#pragma unroll
    for (int k = 0; k < KK; ++k) {
        float dy = s_b[2 * k], dx = s_b[2 * k + 1];
        const uint4* wk = &s_w1h[k * 9];
#pragma unroll
        for (int r = 0; r < 3; ++r)
#pragma unroll
            for (int s = 0; s < 3; ++s) {
                const uint4 wq = wk[r * 3 + s];
                dy = fdot2f(uint_as_h2(wq.x), p01[r][s], dy);
                dy = fdot2f(uint_as_h2(wq.y), p2p[r][s], dy);
                dx = fdot2f(uint_as_h2(wq.z), p01[r][s], dx);
                dx = fdot2f(uint_as_h2(wq.w), p2p[r][s], dx);
            }
        pk[k] = h2_as_uint(pkrtz(dy, dx));
    }

    // ---- phase B: uint2 gather + pk-f16 bilinear + fdot2 conv2 ----
    const float fi = (float)(i + PADR);
    const float fj = (float)(j + PADC);
    float acc0 = s_b2[0], acc1 = s_b2[1], acc2 = s_b2[2];

#pragma unroll
    for (int k = 0; k < KK; ++k) {
        const uint4 wa = s_w2a[k];
        const uint2 wb = s_w2b[k];
        const h2 d = uint_as_h2(pk[k]);
        const float syp = fi + (float)(k / 3) + (float)d.x;  // always > 0
        const float sxp = fj + (float)(k % 3) + (float)d.y;  // always > 0
        const int y0 = (int)syp;  // trunc == floor
        const int x0 = (int)sxp;
        const float fy = syp - (float)y0;
        const float fx = sxp - (float)x0;

        const int a00 = y0 * PC + x0;
        const uint2 c00 = xb2[a00];
        const uint2 c01 = xb2[a00 + 1];
        const uint2 c10 = xb2[a00 + PC];
        const uint2 c11 = xb2[a00 + PC + 1];

        const float wy0 = 1.f - fy, wx0 = 1.f - fx;
        const float w00 = wy0 * wx0, w01 = wy0 * fx;
        const float w10 = fy * wx0, w11 = fy * fx;
        const h2 h00 = pkrtz(w00, w00);
        const h2 h01 = pkrtz(w01, w01);
        const h2 h10 = pkrtz(w10, w10);
        const h2 h11 = pkrtz(w11, w11);

        h2 vg = h00 * uint_as_h2(c00.x);
        vg = h01 * uint_as_h2(c01.x) + vg;
        vg = h10 * uint_as_h2(c10.x) + vg;
        vg = h11 * uint_as_h2(c11.x) + vg;
        h2 ve = h00 * uint_as_h2(c00.y);
        ve = h01 * uint_as_h2(c01.y) + ve;
        ve = h10 * uint_as_h2(c10.y) + ve;
        ve = h11 * uint_as_h2(c11.y) + ve;

        acc0 = fdot2f(uint_as_h2(wa.x), vg, fdot2f(uint_as_h2(wa.y), ve, acc0));
        acc1 = fdot2f(uint_as_h2(wa.z), vg, fdot2f(uint_as_h2(wa.w), ve, acc1));
        acc2 = fdot2f(uint_as_h2(wb.x), vg, fdot2f(uint_as_h2(wb.y), ve, acc2));
    }

    float* ob = out + (size_t)b * COUT * HOWO + (size_t)i * WO + j;
    ob[0 * HOWO] = acc0;
    ob[1 * HOWO] = acc1;
    ob[2 * HOWO] = acc2;
}

// ---------------- fallback: R0-style fully fused (no workspace) ----------
__global__ __launch_bounds__(256) void deform_fused_kernel(
    const float* __restrict__ x, const float* __restrict__ w1,
    const float* __restrict__ b1, const float* __restrict__ w2,
    const float* __restrict__ b2, float* __restrict__ out)
{
    __shared__ float s_w1[18 * 27];
    __shared__ float s_b1[18];
    __shared__ float s_w2[COUT * CIN * KK];
    __shared__ float s_b2[COUT];
    for (int t = threadIdx.x; t < 18 * 27; t += blockDim.x) s_w1[t] = w1[t];
    if (threadIdx.x < 18) s_b1[threadIdx.x] = b1[threadIdx.x];
    if (threadIdx.x < COUT * CIN * KK) s_w2[threadIdx.x] = w2[threadIdx.x];
    if (threadIdx.x < COUT) s_b2[threadIdx.x] = b2[threadIdx.x];
    __syncthreads();
    const int idx = blockIdx.x * blockDim.x + threadIdx.x;
    if (idx >= BB * HOWO) return;
    const int j = idx % WO;
    const int tmp = idx / WO;
    const int i = tmp % HO;
    const int b = tmp / HO;
    const float* xb = x + (size_t)b * CIN * HW;
    float patch[CIN][3][3];
#pragma unroll
    for (int c = 0; c < CIN; ++c)
#pragma unroll
        for (int r = 0; r < 3; ++r)
#pragma unroll
            for (int s = 0; s < 3; ++s)
                patch[c][r][s] = xb[c * HW + (i + r) * WW + (j + s)];
    float acc0 = s_b2[0], acc1 = s_b2[1], acc2 = s_b2[2];
#pragma unroll
    for (int k = 0; k < KK; ++k) {
        const int ky = k / 3, kx = k % 3;
        float dy = s_b1[2 * k], dx = s_b1[2 * k + 1];
        const float* wy = &s_w1[(2 * k) * 27];
        const float* wx = &s_w1[(2 * k + 1) * 27];
        int t = 0;
#pragma unroll
    for (int c = 0; c < CIN; ++c)
#pragma unroll
        for (int r = 0; r < 3; ++r)
#pragma unroll
            for (int s = 0; s < 3; ++s, ++t) {
                const float pv = patch[c][r][s];
                dy += pv * wy[t];
                dx += pv * wx[t];
            }
        const float sy = (float)(i + ky) + dy;
        const float sx = (float)(j + kx) + dx;
        const float y0f = floorf(sy), x0f = floorf(sx);
        const float fy = sy - y0f, fx = sx - x0f;
        const int y0 = (int)y0f, x0 = (int)x0f;
        float v0 = 0.f, v1 = 0.f, v2 = 0.f;
#pragma unroll
        for (int cy = 0; cy < 2; ++cy) {
            const int iy = y0 + cy;
            const float wyf = cy ? fy : (1.f - fy);
            const bool vy = (iy >= 0) && (iy < HH);
            const int iyc = iy < 0 ? 0 : (iy > HH - 1 ? HH - 1 : iy);
#pragma unroll
            for (int cx = 0; cx < 2; ++cx) {
                const int ix = x0 + cx;
                const float wxf = cx ? fx : (1.f - fx);
                const bool vx = (ix >= 0) && (ix < WW);
                const int ixc = ix < 0 ? 0 : (ix > WW - 1 ? WW - 1 : ix);
                const float wgt = (vy && vx) ? (wyf * wxf) : 0.f;
                const int off = iyc * WW + ixc;
                v0 += wgt * xb[0 * HW + off];
                v1 += wgt * xb[1 * HW + off];
                v2 += wgt * xb[2 * HW + off];
            }
        }
#pragma unroll
        for (int o = 0; o < COUT; ++o) {
            const float c0 = s_w2[(o * CIN + 0) * KK + k];
            const float c1 = s_w2[(o * CIN + 1) * KK + k];
            const float c2 = s_w2[(o * CIN + 2) * KK + k];
            const float contrib = c0 * v0 + c1 * v1 + c2 * v2;
            if (o == 0) acc0 += contrib;
            else if (o == 1) acc1 += contrib;
            else acc2 += contrib;
        }
    }
    float* ob = out + (size_t)b * COUT * HOWO + (size_t)i * WO + j;
    ob[0 * HOWO] = acc0;
    ob[1 * HOWO] = acc1;
    ob[2 * HOWO] = acc2;
}

extern "C" void kernel_launch(void* const* d_in, const int* in_sizes, int n_in,
                              void* d_out, int out_size, void* d_ws, size_t ws_size,
                              hipStream_t stream) {
    const float* x  = (const float*)d_in[0];
    const float* w1 = (const float*)d_in[1];
    const float* b1 = (const float*)d_in[2];
    const float* w2 = (const float*)d_in[3];
    const float* b2 = (const float*)d_in[4];
    float* out = (float*)d_out;

    if (ws_size >= XP_BYTES) {
        uint2* xp = (uint2*)d_ws;
        {
            const int total = BB * PR * (PC / 2);
            repack_padh2<<<(total + 255) / 256, 256, 0, stream>>>(x, xp);
        }
        {
            const int total = BB * HOWO;
            deform_fused9<<<(total + 255) / 256, 256, 0, stream>>>(
                xp, w1, b1, w2, b2, out);
        }
    } else {
        const int total = BB * HOWO;
        deform_fused_kernel<<<(total + 255) / 256, 256, 0, stream>>>(
            x, w1, b1, w2, b2, out);
    }
}